// Round 11
// baseline (810.639 us; speedup 1.0000x reference)
//
#include <hip/hip_runtime.h>
#include <math.h>
#include <stdint.h>

#define N_HEADS 4
#define N_NODES 10000
#define NPAD 10112           /* multiple of 128 */
#define NPG (NPAD / 32)      /* 316 node-groups of 32 */
#define EMB 128
#define N_BATCH 4096
#define NQ (2 * N_BATCH)     /* 8192 queries: [src(4096), dst(4096)] */
#define K 8
#define TQ 64                /* queries per block (two 32-row MFMA tiles) */
#define TN 128               /* nodes per iteration (4 groups of 32) */
#define NTILES (NPAD / TN)   /* 79 */
#define PH 2                 /* warm-up tiles (256 nodes) */
#define CAP 41               /* per-query candidate list capacity (odd) */

typedef __attribute__((ext_vector_type(8))) __bf16 bf16x8;
typedef __attribute__((ext_vector_type(8))) unsigned short ushortx8;
typedef __attribute__((ext_vector_type(16))) float floatx16;

// ---------------------------------------------------------------------------
// helpers
// ---------------------------------------------------------------------------
__device__ __forceinline__ unsigned short f2bf(float x) {
  unsigned u = __float_as_uint(x);
  u += 0x7fff + ((u >> 16) & 1);           // round-to-nearest-even
  return (unsigned short)(u >> 16);
}
__device__ __forceinline__ float bf2f(unsigned short h) {
  return __uint_as_float(((unsigned)h) << 16);
}
// bf16 bits rounded toward +inf (conservative threshold)
__device__ __forceinline__ uint32_t bfup(float f) {
  uint32_t u = __float_as_uint(f);
  return (f >= 0.f) ? ((u + 0xFFFFu) >> 16) : (u >> 16);
}

// sorted ascending top-8 insertion
__device__ __forceinline__ void insert8(float* bs, int* bi, float s, int node) {
  if (s < bs[K - 1]) {
    #pragma unroll
    for (int k2 = K - 1; k2 >= 0; --k2) {
      if (!(s < bs[k2])) break;
      if (k2 < K - 1) { bs[k2 + 1] = bs[k2]; bi[k2 + 1] = bi[k2]; }
      bs[k2] = s; bi[k2] = node;
    }
  }
}

// permuted chunk offset (in ushorts) for row (32g+lm), chunk c (c = ks*2+lh)
// layout: [g][ks][lh][lm] x 8 ushorts  => g*4096 + ks*512 + lh*256 + lm*8
__device__ __forceinline__ size_t pchunk(int g, int c, int lm) {
  return (size_t)g * 4096 + (size_t)(c >> 1) * 512 + (size_t)(c & 1) * 256 + lm * 8;
}

// ---------------------------------------------------------------------------
// Kernel P: split E into bf16 hi/lo in MFMA-B-fragment-permuted layout,
// plus y2 norms. Grid (NPG, N_HEADS), 256 thr. (unchanged — verified)
// ---------------------------------------------------------------------------
__global__ __launch_bounds__(256) void prep_kernel(
    const float* __restrict__ E, unsigned short* __restrict__ EhiP,
    unsigned short* __restrict__ EloP, float* __restrict__ y2g) {
  __shared__ float s_p[8][33];
  const int h = blockIdx.y, g = blockIdx.x;
  const int lm = threadIdx.x & 31, c8 = threadIdx.x >> 5;
  const int n = g * 32 + lm;
  float x[16];
  #pragma unroll
  for (int j = 0; j < 16; ++j) x[j] = 0.f;
  if (n < N_NODES) {
    const float* src = E + (size_t)(h * N_NODES + n) * EMB + c8 * 16;
    #pragma unroll
    for (int j = 0; j < 4; ++j) {
      float4 v = *(const float4*)(src + j * 4);
      x[j * 4 + 0] = v.x; x[j * 4 + 1] = v.y; x[j * 4 + 2] = v.z; x[j * 4 + 3] = v.w;
    }
  }
  float part = 0.f;
  ushortx8 hi[2], lo[2];
  #pragma unroll
  for (int j = 0; j < 16; ++j) {
    part += x[j] * x[j];
    unsigned short hv = f2bf(x[j]);
    unsigned short lv = f2bf(x[j] - bf2f(hv));
    hi[j >> 3][j & 7] = hv;
    lo[j >> 3][j & 7] = lv;
  }
  size_t base = (size_t)h * NPG * 4096;
  #pragma unroll
  for (int lh = 0; lh < 2; ++lh) {
    size_t off = base + pchunk(g, c8 * 2 + lh, lm);
    *(ushortx8*)&EhiP[off] = hi[lh];
    *(ushortx8*)&EloP[off] = lo[lh];
  }
  s_p[c8][lm] = part;
  __syncthreads();
  if (threadIdx.x < 32) {
    int nn = g * 32 + threadIdx.x;
    float s = 0.f;
    #pragma unroll
    for (int j = 0; j < 8; ++j) s += s_p[j][threadIdx.x];
    y2g[h * NPAD + nn] = (nn < N_NODES) ? s : 1e30f;
  }
}

// ---------------------------------------------------------------------------
// Kernel A: barrier-free MFMA knn, 64q x 128n per iteration, 512 threads.
// vs R10: TQ 32->64 via 8 waves — wave (w0=wave>>2, w1=wave&3) owns query
// rows 32*w0, node group 4t+w1. The two w0-waves with equal w1 read the
// SAME coalesced B strip ~simultaneously -> L1 hit for the second; per-head
// B cache traffic halves (5.2 GB -> 2.6 GB). Per-wave register content is
// identical to R10 (measured 64 VGPR — fits the 128 cap at 4 waves/EU).
// Query-lo A-frags in LDS (s_alo); thresholds packed round-up bf16 pairs.
// Selection: verified filter-then-refine (R7-R10). score = y2[n]-2*dot.
// ---------------------------------------------------------------------------
__global__ __launch_bounds__(512, 4) void knn_kernel(
    const unsigned short* __restrict__ EhiP, const unsigned short* __restrict__ EloP,
    const float* __restrict__ y2g, const int* __restrict__ be,
    int* __restrict__ samples) {
  __shared__ __align__(16) float s_x[TQ * TN];              // 32 KiB
  __shared__ __align__(16) unsigned short s_alo[TQ * EMB];  // 16 KiB, persistent
  __shared__ float s_t8S[TQ * 9];                           // 2.25 KiB
  __shared__ int   s_t8I[TQ * 9];                           // 2.25 KiB
  __shared__ float s_lsS[TQ * CAP];                         // 10.25 KiB
  __shared__ int   s_lsI[TQ * CAP];                         // 10.25 KiB
  __shared__ float s_thr[TQ];
  __shared__ int   s_cnt[TQ];

  const int id = blockIdx.x;                     // 512 blocks
  const int h = (id & 7) >> 1;                   // head -> XCD pair
  const int qt = ((id >> 3) << 1) | (id & 1);    // 0..127
  const int tid = threadIdx.x;
  const int lane = tid & 63;
  const int wave = tid >> 6;                     // 0..7
  const int w0 = wave >> 2, w1 = wave & 3;
  const int lm = lane & 31, lh = lane >> 5;
  const unsigned short* EhiH = EhiP + (size_t)h * NPG * 4096;
  const unsigned short* EloH = EloP + (size_t)h * NPG * 4096;
  const float* y2H = y2g + h * NPAD;

  // ---- prologue: gather query rows -> s_x (hi, to regs) / s_alo (lo) ----
  bf16x8 ahi[8];
  unsigned short* s_xq = (unsigned short*)s_x;
  const int arow = 32 * w0 + lm;                 // this wave's query rows
  const int arx = arow & 15;
  {
    int r = tid >> 3, cb = (tid & 7) * 2;        // 64 rows x 2 chunks each
    int rx15 = r & 15;
    int q = be[qt * TQ + r];
    int gq = q >> 5, lmq = q & 31;
    #pragma unroll
    for (int c = 0; c < 2; ++c) {
      int lc = cb + c;
      *(bf16x8*)&s_xq[r * EMB + (lc ^ rx15) * 8] =
          *(const bf16x8*)&EhiH[pchunk(gq, lc, lmq)];
    }
    __syncthreads();
    #pragma unroll
    for (int ks = 0; ks < 8; ++ks)
      ahi[ks] = *(const bf16x8*)&s_xq[arow * EMB + (((ks * 2 + lh) ^ arx)) * 8];
    __syncthreads();
    #pragma unroll
    for (int c = 0; c < 2; ++c) {
      int lc = cb + c;
      *(bf16x8*)&s_alo[r * EMB + (lc ^ rx15) * 8] =
          *(const bf16x8*)&EloH[pchunk(gq, lc, lmq)];
    }
    __syncthreads();
  }

  // warm-up scan roles: 8 threads per query, each owns a 16-col stripe
  const int qsel = tid >> 3;                     // 0..63
  const int csel = tid & 7;                      // 0..7
  const int myq = be[qt * TQ + qsel];
  float bs[K]; int bi[K];
  #pragma unroll
  for (int k2 = 0; k2 < K; ++k2) { bs[k2] = 1e30f; bi[k2] = 0x7fffffff; }
  if (tid < TQ) s_cnt[tid] = 0;

  const int bnode = 32 * w1 + lm;                // node within 128-tile
  const unsigned short* bhp = EhiH + (size_t)w1 * 4096 + lane * 8;
  const unsigned short* blp = EloH + (size_t)w1 * 4096 + lane * 8;

  // ---- warm-up: PH tiles via score dump + private insert ----
  #pragma unroll 1
  for (int t = 0; t < PH; ++t) {
    const size_t goff = (size_t)t * 16384;       // 4 groups * 4096 ushorts
    float ny = y2H[t * TN + bnode];
    floatx16 acc = {0.f, 0.f, 0.f, 0.f, 0.f, 0.f, 0.f, 0.f,
                    0.f, 0.f, 0.f, 0.f, 0.f, 0.f, 0.f, 0.f};
    #pragma unroll
    for (int ks = 0; ks < 8; ++ks) {
      bf16x8 va = *(const bf16x8*)&s_alo[arow * EMB + (((ks * 2 + lh) ^ arx)) * 8];
      bf16x8 vbh = *(const bf16x8*)(bhp + goff + ks * 512);
      bf16x8 vbl = *(const bf16x8*)(blp + goff + ks * 512);
      acc = __builtin_amdgcn_mfma_f32_32x32x16_bf16(va, vbh, acc, 0, 0, 0);
      acc = __builtin_amdgcn_mfma_f32_32x32x16_bf16(ahi[ks], vbl, acc, 0, 0, 0);
      acc = __builtin_amdgcn_mfma_f32_32x32x16_bf16(ahi[ks], vbh, acc, 0, 0, 0);
    }
    #pragma unroll
    for (int r = 0; r < 16; ++r) {
      int row = 32 * w0 + (r & 3) + 8 * (r >> 2) + 4 * lh;
      s_x[row * TN + bnode] = fmaf(-2.f, acc[r], ny);
    }
    __syncthreads();
    int nbp = t * TN;
    #pragma unroll
    for (int s = 0; s < 16; ++s) {
      int j = csel * 16 + ((s + qsel) & 15);
      float sc = s_x[qsel * TN + j];
      int node = nbp + j;
      if (node != myq) insert8(bs, bi, sc, node);
    }
    __syncthreads();
  }

  // ---- first merge: privates -> exact top-8 + thresholds ----
  {
    float* scrS = (float*)s_x;                   // 4096 floats
    int*   scrI = (int*)s_x + TQ * 64;           // 4096 ints
    #pragma unroll
    for (int k2 = 0; k2 < K; ++k2) {
      scrS[tid * 8 + k2] = bs[k2]; scrI[tid * 8 + k2] = bi[k2];
    }
    __syncthreads();
    if (tid < TQ) {
      int q = tid;
      float ts[K]; int ti[K];
      #pragma unroll
      for (int k2 = 0; k2 < K; ++k2) { ts[k2] = 1e30f; ti[k2] = 0x7fffffff; }
      for (int kk = 0; kk < 64; ++kk) {
        int e = (kk + q) & 63;                   // bank-rotated scan
        insert8(ts, ti, scrS[q * 64 + e], scrI[q * 64 + e]);
      }
      s_thr[q] = ts[K - 1];
      #pragma unroll
      for (int k2 = 0; k2 < K; ++k2) { s_t8S[q * 9 + k2] = ts[k2]; s_t8I[q * 9 + k2] = ti[k2]; }
    }
    __syncthreads();
  }

  // packed round-up bf16 thresholds: 8 regs for 16 rows
  uint32_t thrp[8];
  #pragma unroll
  for (int j = 0; j < 8; ++j) {
    int r0 = 2 * j, r1 = 2 * j + 1;
    float t0 = s_thr[32 * w0 + (r0 & 3) + 8 * (r0 >> 2) + 4 * lh];
    float t1 = s_thr[32 * w0 + (r1 & 3) + 8 * (r1 >> 2) + 4 * lh];
    thrp[j] = bfup(t0) | (bfup(t1) << 16);
  }

  // ---- steady state: barrier-free tiles with in-register filtering ----
  #pragma unroll 1
  for (int t = PH; t < NTILES; ++t) {
    if (t == 4 || t == 8 || t == 16 || t == 32) {   // merge point
      __syncthreads();
      if (tid < TQ) {
        int q = tid;
        int myqm = be[qt * TQ + q];
        float ts[K]; int ti[K];
        #pragma unroll
        for (int k2 = 0; k2 < K; ++k2) { ts[k2] = s_t8S[q * 9 + k2]; ti[k2] = s_t8I[q * 9 + k2]; }
        int cnt = s_cnt[q]; if (cnt > CAP) cnt = CAP;
        for (int p = 0; p < cnt; ++p) {
          int iv = s_lsI[q * CAP + p];
          if (iv != myqm) insert8(ts, ti, s_lsS[q * CAP + p], iv);
        }
        s_cnt[q] = 0;
        s_thr[q] = ts[K - 1];
        #pragma unroll
        for (int k2 = 0; k2 < K; ++k2) { s_t8S[q * 9 + k2] = ts[k2]; s_t8I[q * 9 + k2] = ti[k2]; }
      }
      __syncthreads();
      #pragma unroll
      for (int j = 0; j < 8; ++j) {
        int r0 = 2 * j, r1 = 2 * j + 1;
        float t0 = s_thr[32 * w0 + (r0 & 3) + 8 * (r0 >> 2) + 4 * lh];
        float t1 = s_thr[32 * w0 + (r1 & 3) + 8 * (r1 >> 2) + 4 * lh];
        thrp[j] = bfup(t0) | (bfup(t1) << 16);
      }
    }

    const size_t goff = (size_t)t * 16384;
    float ny = y2H[t * TN + bnode];
    floatx16 acc = {0.f, 0.f, 0.f, 0.f, 0.f, 0.f, 0.f, 0.f,
                    0.f, 0.f, 0.f, 0.f, 0.f, 0.f, 0.f, 0.f};
    #pragma unroll
    for (int ks = 0; ks < 8; ++ks) {
      bf16x8 va = *(const bf16x8*)&s_alo[arow * EMB + (((ks * 2 + lh) ^ arx)) * 8];
      bf16x8 vbh = *(const bf16x8*)(bhp + goff + ks * 512);
      bf16x8 vbl = *(const bf16x8*)(blp + goff + ks * 512);
      acc = __builtin_amdgcn_mfma_f32_32x32x16_bf16(va, vbh, acc, 0, 0, 0);
      acc = __builtin_amdgcn_mfma_f32_32x32x16_bf16(ahi[ks], vbl, acc, 0, 0, 0);
      acc = __builtin_amdgcn_mfma_f32_32x32x16_bf16(ahi[ks], vbh, acc, 0, 0, 0);
    }
    const int node = t * TN + bnode;
    #pragma unroll
    for (int r = 0; r < 16; ++r) {
      float sc = fmaf(-2.f, acc[r], ny);
      float th = (r & 1) ? __uint_as_float(thrp[r >> 1] & 0xFFFF0000u)
                         : __uint_as_float(thrp[r >> 1] << 16);
      if (sc < th) {                             // rare (self or new top-8)
        int q = 32 * w0 + (r & 3) + 8 * (r >> 2) + 4 * lh;
        int p = atomicAdd(&s_cnt[q], 1);
        if (p < CAP) { s_lsS[q * CAP + p] = sc; s_lsI[q * CAP + p] = node; }
      }
    }
  }

  // ---- final merge + writeout ----
  __syncthreads();
  if (tid < TQ) {
    int q = tid;
    int myqm = be[qt * TQ + q];
    float ts[K]; int ti[K];
    #pragma unroll
    for (int k2 = 0; k2 < K; ++k2) { ts[k2] = s_t8S[q * 9 + k2]; ti[k2] = s_t8I[q * 9 + k2]; }
    int cnt = s_cnt[q]; if (cnt > CAP) cnt = CAP;
    for (int p = 0; p < cnt; ++p) {
      int iv = s_lsI[q * CAP + p];
      if (iv != myqm) insert8(ts, ti, s_lsS[q * CAP + p], iv);
    }
    size_t base = ((size_t)h * NQ + qt * TQ + q) * K;
    #pragma unroll
    for (int k2 = 0; k2 < K; ++k2) samples[base + k2] = ti[k2];
  }
}

// ---------------------------------------------------------------------------
// Kernel B: epilogue (unchanged — verified absmax 0.0).
// ---------------------------------------------------------------------------
__global__ __launch_bounds__(256) void predict_kernel(
    const float* __restrict__ E, const float* __restrict__ F,
    const float* __restrict__ unc, const float* __restrict__ adj,
    const int* __restrict__ be, const int* __restrict__ samples,
    float* __restrict__ out) {
  int b = blockIdx.x;
  int h = threadIdx.x >> 6;
  int lane = threadIdx.x & 63;
  __shared__ float smv[N_HEADS];

  int srcb = be[b];
  int dstb = be[N_BATCH + b];
  const float* Eh = E + (size_t)h * N_NODES * EMB;
  const float* Fh = F + (size_t)h * N_NODES * EMB;
  float2 es = *(const float2*)(Eh + (size_t)srcb * EMB + 2 * lane);
  float2 ed = *(const float2*)(Eh + (size_t)dstb * EMB + 2 * lane);
  float2 fs = *(const float2*)(Fh + (size_t)srcb * EMB + 2 * lane);
  float2 fd = *(const float2*)(Fh + (size_t)dstb * EMB + 2 * lane);
  float u = unc[0];

  float logit[16], dist[16];
  #pragma unroll
  for (int j = 0; j < 16; ++j) {
    bool isrc = (j < 8);
    int qrow = isrc ? b : (N_BATCH + b);
    int s = samples[((size_t)h * NQ + qrow) * K + (j & 7)];
    float2 ev = *(const float2*)(Eh + (size_t)s * EMB + 2 * lane);
    float2 bb = isrc ? es : ed;
    float2 g = isrc ? fd : fs;
    float dx = bb.x - ev.x, dy = bb.y - ev.y;
    float dot = dx * g.x + dy * g.y;
    float nrm = dx * dx + dy * dy;
    #pragma unroll
    for (int o = 32; o > 0; o >>= 1) {
      dot += __shfl_xor(dot, o);
      nrm += __shfl_xor(nrm, o);
    }
    float a = isrc ? adj[(size_t)s * N_NODES + dstb]
                   : adj[(size_t)srcb * N_NODES + s];
    logit[j] = dot + u * (2.0f * a - 1.0f);
    dist[j] = sqrtf(nrm);
  }

  float m = 0.0f;  // sentinel: 1 - 1.0 = 0
  #pragma unroll
  for (int j = 0; j < 16; ++j) m = fmaxf(m, 1.0f - dist[j]);
  float Z = 8.0f * expf(-m);
  float num = 0.0f;
  #pragma unroll
  for (int j = 0; j < 16; ++j) {
    float e = expf(1.0f - dist[j] - m);
    Z += e;
    num += logit[j] * e;
  }
  if (lane == 0) smv[h] = num / Z;
  __syncthreads();
  if (threadIdx.x == 0) {
    float t = 0.25f * (smv[0] + smv[1] + smv[2] + smv[3]);
    out[b] = 1.0f / (1.0f + expf(-t));
  }
}

// ---------------------------------------------------------------------------
extern "C" void kernel_launch(void* const* d_in, const int* in_sizes, int n_in,
                              void* d_out, int out_size, void* d_ws,
                              size_t ws_size, hipStream_t stream) {
  const float* E = (const float*)d_in[0];
  const float* F = (const float*)d_in[1];
  const float* U = (const float*)d_in[2];
  const float* A = (const float*)d_in[3];
  const int* be = (const int*)d_in[4];
  float* out = (float*)d_out;

  // ws layout (256B-aligned): EhiP 10,354,688 | EloP 10,354,688 |
  //   y2g 162,048 | samples 1,048,576   (~21.9 MB)
  char* w = (char*)d_ws;
  unsigned short* EhiP = (unsigned short*)(w);
  unsigned short* EloP = (unsigned short*)(w + 10354688);
  float* y2g = (float*)(w + 20709376);
  int* samples = (int*)(w + 20871424);

  prep_kernel<<<dim3(NPG, N_HEADS), 256, 0, stream>>>(E, EhiP, EloP, y2g);
  knn_kernel<<<dim3((NQ / TQ) * N_HEADS), 512, 0, stream>>>(EhiP, EloP, y2g, be, samples);
  predict_kernel<<<dim3(N_BATCH), 256, 0, stream>>>(E, F, U, A, be, samples, out);
}